// Round 10
// baseline (55.506 us; speedup 1.0000x reference)
//
#include <hip/hip_runtime.h>
#include <hip/hip_fp16.h>

#define NN   2048
#define FIN  128
#define FOUT 64
#define LOG2E 1.44269504088896f

using f16x8 = __attribute__((ext_vector_type(8))) _Float16;
using f16x4 = __attribute__((ext_vector_type(4))) _Float16;
using f16x2 = __attribute__((ext_vector_type(2))) _Float16;
using f32x4 = __attribute__((ext_vector_type(4))) float;
using i32x4 = __attribute__((ext_vector_type(4))) int;

__device__ inline float fast_exp2(float x) {
#if __has_builtin(__builtin_amdgcn_exp2f)
    return __builtin_amdgcn_exp2f(x);
#else
    return exp2f(x);
#endif
}

// h16B frag-ordered layout, per (bh): halves offset =
//   bh*131072 + (j>>5)*2048 + (o>>4)*512 + (((j>>3)&3)*16 + (o&15))*8 + (j&7)
// adjbits layout (ROW-MAJOR, dense): [flat_row(8192)][wc(64)] u32

// ---------------------------------------------------------------------------
// Kernel 1: h = x @ w[h] (fp32) + tanh -> s_src/s_dst (log2e-scaled) + h->fp16
// frag order + adj bitpack (dense row-major). 512 blocks x 256 threads.
// ---------------------------------------------------------------------------
__global__ __launch_bounds__(256) void k1_proj(
    const float* __restrict__ x, const float* __restrict__ w,
    const float* __restrict__ a_src, const float* __restrict__ a_dst,
    const int* __restrict__ adj,
    _Float16* __restrict__ h16B, float* __restrict__ ssrc, float* __restrict__ sdst,
    unsigned int* __restrict__ adjbits)
{
    __shared__ __align__(16) float w_s[FIN * FOUT];
    __shared__ __align__(16) float xs[64 * 132];

    const int t    = threadIdx.x;
    const int bx   = blockIdx.x;
    const int bh   = bx >> 5;
    const int tile = bx & 31;
    const int b    = bh >> 2;
    const int h    = bh & 3;
    const int n0   = tile * 64;

    {
        const f32x4* wg = (const f32x4*)(w + h * FIN * FOUT);
        f32x4* wl = (f32x4*)w_s;
#pragma unroll
        for (int k = 0; k < 8; ++k) wl[t + 256 * k] = wg[t + 256 * k];
    }
    {
#pragma unroll
        for (int k = 0; k < 8; ++k) {
            int q  = t + 256 * k;
            int r  = q >> 5;
            int c4 = q & 31;
            f32x4 v = *(const f32x4*)(x + (size_t)(b * NN + n0 + r) * FIN + c4 * 4);
            *(f32x4*)(xs + r * 132 + c4 * 4) = v;
        }
    }
    __syncthreads();

    const int ty = t >> 4, tx = t & 15;
    float acc[4][4] = {};

#pragma unroll 4
    for (int f4 = 0; f4 < 32; ++f4) {
        f32x4 xv[4], wv[4];
#pragma unroll
        for (int q = 0; q < 4; ++q)
            xv[q] = *(const f32x4*)(xs + (ty * 4 + q) * 132 + f4 * 4);
#pragma unroll
        for (int k = 0; k < 4; ++k)
            wv[k] = *(const f32x4*)(w_s + (f4 * 4 + k) * 64 + tx * 4);
#pragma unroll
        for (int q = 0; q < 4; ++q)
#pragma unroll
            for (int k = 0; k < 4; ++k)
#pragma unroll
                for (int c = 0; c < 4; ++c)
                    acc[q][c] += xv[q][k] * wv[k][c];
    }

    const int j0 = n0 + ty * 4;
#pragma unroll
    for (int cc = 0; cc < 4; ++cc) {
        int o = tx * 4 + cc;
        f16x4 hv;
#pragma unroll
        for (int q = 0; q < 4; ++q) hv[q] = (_Float16)acc[q][cc];
        int off = bh * 131072 + (j0 >> 5) * 2048 + (o >> 4) * 512
                + (((j0 >> 3) & 3) * 16 + (o & 15)) * 8 + (j0 & 7);
        *(f16x4*)(h16B + off) = hv;
    }

    f32x4 a_s = *(const f32x4*)(a_src + h * FOUT + tx * 4);
    f32x4 a_d = *(const f32x4*)(a_dst + h * FOUT + tx * 4);
    float ss[4], sd[4];
#pragma unroll
    for (int q = 0; q < 4; ++q) {
        float s1 = 0.f, s2 = 0.f;
#pragma unroll
        for (int cc = 0; cc < 4; ++cc) {
            float th = tanhf(acc[q][cc]);
            s1 += th * a_s[cc];
            s2 += th * a_d[cc];
        }
        ss[q] = s1; sd[q] = s2;
    }
#pragma unroll
    for (int m = 1; m <= 8; m <<= 1) {
#pragma unroll
        for (int q = 0; q < 4; ++q) {
            ss[q] += __shfl_xor(ss[q], m);
            sd[q] += __shfl_xor(sd[q], m);
        }
    }
    if (tx == 0) {
#pragma unroll
        for (int q = 0; q < 4; ++q) {
            ssrc[bh * NN + j0 + q] = ss[q] * LOG2E;   // pre-scale: exp -> exp2
            sdst[bh * NN + j0 + q] = sd[q] * LOG2E;
        }
    }

    // ---- adj bitpack: block bx packs flat rows [bx*16, bx*16+16), DENSE ----
    {
        const int  frow0 = bx * 16;
        const int* asrc  = adj + (size_t)frow0 * NN;
#pragma unroll
        for (int w4 = 0; w4 < 4; ++w4) {
            int widx  = t + 256 * w4;          // 0..1023
            int row_l = widx >> 6;
            int wc    = widx & 63;
            const i32x4* p = (const i32x4*)(asrc + (size_t)row_l * NN + wc * 32);
            unsigned int wbits = 0;
#pragma unroll
            for (int k = 0; k < 8; ++k) {
                i32x4 v = p[k];
                wbits |= (unsigned int)(v[0] & 1) << (4 * k);
                wbits |= (unsigned int)(v[1] & 1) << (4 * k + 1);
                wbits |= (unsigned int)(v[2] & 1) << (4 * k + 2);
                wbits |= (unsigned int)(v[3] & 1) << (4 * k + 3);
            }
            adjbits[(size_t)(frow0 + row_l) * 64 + wc] = wbits;
        }
    }
}

// ---------------------------------------------------------------------------
// Kernel 2: LDS-instruction-minimal masked-softmax attention + PV.
// 512 blocks (16 bh x 32 tiles of 64 rows) x 256 threads (4 waves).
// Wave (rgp = wv>>1, par = wv&1): owns 2 row-groups (rga=2rgp, rgb=2rgp+1)
// and j-half par. Per 64-j step: B-frags read ONCE per wave and shared
// across both rgs (kills the 4x duplication), sd reads shared, exp2-direct
// e-gen, 10 MFMAs. LDS per wave-step: 6 b128 + 2 b32.
// LDS 41.4 KB -> 3 blocks/CU.
// ---------------------------------------------------------------------------
__global__ __launch_bounds__(256, 3) void k2_attn(
    const unsigned int* __restrict__ adjbits,
    const _Float16* __restrict__ h16B,
    const float* __restrict__ ssrc, const float* __restrict__ sdst,
    const float* __restrict__ bias, float* __restrict__ out)
{
    // smem: [0,16K) Bf dbuf 2x8KB | [16384,+17408) adjw 64x68 | [33792,+8K) sd
    //       | [41984,+16) redmax. comb (21KB, stride 41) overlays [0,21K).
    __shared__ __align__(16) char smem[42000];
    _Float16*     Bf     = (_Float16*)smem;
    unsigned int* adjw   = (unsigned int*)(smem + 16384);  // stride 68 words
    float*        sd_lds = (float*)(smem + 33792);
    float*        redmax = (float*)(smem + 41984);
    float*        comb   = (float*)smem;

    const int t    = threadIdx.x;
    const int wv   = t >> 6;
    const int lane = t & 63;
    const int bh   = blockIdx.x >> 5;
    const int i0   = (blockIdx.x & 31) << 6;    // 64-row tile
    const int b    = bh >> 2;
    const int rgp  = wv >> 1;
    const int par  = wv & 1;
    const int m    = lane & 15;
    const int g    = lane >> 4;
    const int rga  = rgp * 2;
    const int rgb  = rgp * 2 + 1;

    const _Float16* Bsrc = h16B + bh * 131072;

#define STAGE(bufi_, s_) do {                                                   \
    __builtin_amdgcn_global_load_lds(                                           \
        (const __attribute__((address_space(1))) unsigned int*)(Bsrc + (s_) * 4096 + t * 8), \
        (__attribute__((address_space(3))) unsigned int*)(Bf + (bufi_) * 4096 + t * 8), \
        16, 0, 0);                                                              \
    __builtin_amdgcn_global_load_lds(                                           \
        (const __attribute__((address_space(1))) unsigned int*)(Bsrc + (s_) * 4096 + 2048 + t * 8), \
        (__attribute__((address_space(3))) unsigned int*)(Bf + (bufi_) * 4096 + 2048 + t * 8), \
        16, 0, 0);                                                              \
    } while (0)

    // ---- prologue ----
    STAGE(0, 0);
    // adj slab 16 KB -> padded (stride 68) LDS via reg-stage
    {
        const uint4* asrc = (const uint4*)(adjbits + ((size_t)b * NN + i0) * 64);
#pragma unroll
        for (int k = 0; k < 4; ++k) {
            int idx = t + 256 * k;                  // 0..1023 uint4s; 16 per row
            uint4 v = asrc[idx];
            *(uint4*)(adjw + (idx >> 4) * 68 + (idx & 15) * 4) = v;
        }
    }
    // sd 8 KB via global_load_lds
    __builtin_amdgcn_global_load_lds(
        (const __attribute__((address_space(1))) unsigned int*)(sdst + bh * NN + t * 4),
        (__attribute__((address_space(3))) unsigned int*)(sd_lds + t * 4), 16, 0, 0);
    __builtin_amdgcn_global_load_lds(
        (const __attribute__((address_space(1))) unsigned int*)(sdst + bh * NN + 1024 + t * 4),
        (__attribute__((address_space(3))) unsigned int*)(sd_lds + 1024 + t * 4), 16, 0, 0);

    const float sA_a = ssrc[bh * NN + i0 + rga * 16 + m];
    const float sA_b = ssrc[bh * NN + i0 + rgb * 16 + m];

    asm volatile("s_waitcnt vmcnt(0)" ::: "memory");
    __syncthreads();

    // ---- D = max_j sd ----
    {
        f32x4 d0 = *(const f32x4*)(sd_lds + t * 8);
        f32x4 d1 = *(const f32x4*)(sd_lds + t * 8 + 4);
        float dm = fmaxf(fmaxf(fmaxf(d0[0], d0[1]), fmaxf(d0[2], d0[3])),
                         fmaxf(fmaxf(d1[0], d1[1]), fmaxf(d1[2], d1[3])));
#pragma unroll
        for (int msk = 1; msk <= 32; msk <<= 1) dm = fmaxf(dm, __shfl_xor(dm, msk));
        if (lane == 0) redmax[wv] = dm;
    }
    __syncthreads();
    const float D = fmaxf(fmaxf(redmax[0], redmax[1]), fmaxf(redmax[2], redmax[3]));

    float c_a = sA_a + D; c_a = fmaxf(c_a, 0.2f * c_a);
    float c_b = sA_b + D; c_b = fmaxf(c_b, 0.2f * c_b);
    const float sAc_a  = sA_a - c_a;
    const float sAc2_a = fmaf(0.2f, sA_a, -c_a);
    const float sAc_b  = sA_b - c_b;
    const float sAc2_b = fmaf(0.2f, sA_b, -c_b);

    f32x4 aA0 = {0,0,0,0}, aA1 = {0,0,0,0}, aA2 = {0,0,0,0}, aA3 = {0,0,0,0};
    f32x4 aB0 = {0,0,0,0}, aB1 = {0,0,0,0}, aB2 = {0,0,0,0}, aB3 = {0,0,0,0};
    f32x4 zA = {0,0,0,0}, zB = {0,0,0,0};
    f16x8 ones;
#pragma unroll
    for (int i = 0; i < 8; ++i) ones[i] = (_Float16)1.0f;

    const int arowA = (rga * 16 + m) * 68;
    const int arowB = (rgb * 16 + m) * 68;

    for (int s = 0; s < 32; ++s) {
        if (s < 31) {
            STAGE((s + 1) & 1, s + 1);
            asm volatile("s_waitcnt vmcnt(2)" ::: "memory");  // stage(s) done
        } else {
            asm volatile("s_waitcnt vmcnt(0)" ::: "memory");
        }
        __builtin_amdgcn_sched_barrier(0);
        __builtin_amdgcn_s_barrier();
        __builtin_amdgcn_sched_barrier(0);

        const int ci = 2 * s + par;                 // 32-j word-col
        unsigned int wbA = adjw[arowA + ci] >> (8 * g);
        unsigned int wbB = adjw[arowB + ci] >> (8 * g);
        const float* djp = sd_lds + ci * 32 + 8 * g;
        f32x4 dj0 = *(const f32x4*)(djp);
        f32x4 dj1 = *(const f32x4*)(djp + 4);

        const _Float16* bb = Bf + (s & 1) * 4096 + par * 2048 + lane * 8;
        f16x8 b0 = *(const f16x8*)(bb);
        f16x8 b1 = *(const f16x8*)(bb + 512);
        f16x8 b2 = *(const f16x8*)(bb + 1024);
        f16x8 b3 = *(const f16x8*)(bb + 1536);

        float evA[8], evB[8];
#pragma unroll
        for (int i = 0; i < 8; ++i) {
            float dj = (i < 4) ? dj0[i] : dj1[i - 4];
            float eA = fast_exp2(fmaxf(sAc_a + dj, fmaf(0.2f, dj, sAc2_a)));
            float eB = fast_exp2(fmaxf(sAc_b + dj, fmaf(0.2f, dj, sAc2_b)));
            evA[i] = (wbA & (1u << i)) ? eA : 0.0f;
            evB[i] = (wbB & (1u << i)) ? eB : 0.0f;
        }
        union { f16x8 v; f16x2 p[4]; } afA, afB;
#pragma unroll
        for (int i = 0; i < 4; ++i) {
            afA.p[i] = __builtin_bit_cast(f16x2,
                __builtin_amdgcn_cvt_pkrtz(evA[2 * i], evA[2 * i + 1]));
            afB.p[i] = __builtin_bit_cast(f16x2,
                __builtin_amdgcn_cvt_pkrtz(evB[2 * i], evB[2 * i + 1]));
        }

        aA0 = __builtin_amdgcn_mfma_f32_16x16x32_f16(afA.v, b0, aA0, 0, 0, 0);
        aA1 = __builtin_amdgcn_mfma_f32_16x16x32_f16(afA.v, b1, aA1, 0, 0, 0);
        aA2 = __builtin_amdgcn_mfma_f32_16x16x32_f16(afA.v, b2, aA2, 0, 0, 0);
        aA3 = __builtin_amdgcn_mfma_f32_16x16x32_f16(afA.v, b3, aA3, 0, 0, 0);
        zA  = __builtin_amdgcn_mfma_f32_16x16x32_f16(afA.v, ones, zA, 0, 0, 0);
        aB0 = __builtin_amdgcn_mfma_f32_16x16x32_f16(afB.v, b0, aB0, 0, 0, 0);
        aB1 = __builtin_amdgcn_mfma_f32_16x16x32_f16(afB.v, b1, aB1, 0, 0, 0);
        aB2 = __builtin_amdgcn_mfma_f32_16x16x32_f16(afB.v, b2, aB2, 0, 0, 0);
        aB3 = __builtin_amdgcn_mfma_f32_16x16x32_f16(afB.v, b3, aB3, 0, 0, 0);
        zB  = __builtin_amdgcn_mfma_f32_16x16x32_f16(afB.v, ones, zB, 0, 0, 0);

        __builtin_amdgcn_s_barrier();   // protect buf before next overwrite
    }
#undef STAGE

    // ---- combine parity partials (comb overlays Bf/adjw; stride 41) ----
    __syncthreads();
    if (par == 1) {
        float* cp = comb + (rgp * 64 + lane) * 41;
#pragma unroll
        for (int r = 0; r < 4; ++r) {
            cp[0 + r]  = aA0[r]; cp[4 + r]  = aA1[r];
            cp[8 + r]  = aA2[r]; cp[12 + r] = aA3[r];
            cp[16 + r] = zA[r];
            cp[20 + r] = aB0[r]; cp[24 + r] = aB1[r];
            cp[28 + r] = aB2[r]; cp[32 + r] = aB3[r];
            cp[36 + r] = zB[r];
        }
    }
    __syncthreads();
    if (par == 0) {
        const float* cp = comb + (rgp * 64 + lane) * 41;
        float zsA[4], zsB[4];
#pragma unroll
        for (int r = 0; r < 4; ++r) {
            zsA[r] = zA[r] + cp[16 + r];
            zsB[r] = zB[r] + cp[36 + r];
        }
        // C/D layout: col = lane&15, row = g*4 + r
        size_t obaseA = ((size_t)bh * NN + i0 + rga * 16) * FOUT;
        size_t obaseB = ((size_t)bh * NN + i0 + rgb * 16) * FOUT;
#pragma unroll
        for (int ot = 0; ot < 4; ++ot) {
            float bv = bias[ot * 16 + m];
            f32x4 aA = (ot == 0) ? aA0 : (ot == 1) ? aA1 : (ot == 2) ? aA2 : aA3;
            f32x4 aB = (ot == 0) ? aB0 : (ot == 1) ? aB1 : (ot == 2) ? aB2 : aB3;
#pragma unroll
            for (int r = 0; r < 4; ++r) {
                float vA = (aA[r] + cp[ot * 4 + r])      / zsA[r] + bv;
                float vB = (aB[r] + cp[20 + ot * 4 + r]) / zsB[r] + bv;
                out[obaseA + (size_t)(g * 4 + r) * FOUT + ot * 16 + m] = vA;
                out[obaseB + (size_t)(g * 4 + r) * FOUT + ot * 16 + m] = vB;
            }
        }
    }
}

// ---------------------------------------------------------------------------
extern "C" void kernel_launch(void* const* d_in, const int* in_sizes, int n_in,
                              void* d_out, int out_size, void* d_ws, size_t ws_size,
                              hipStream_t stream) {
    (void)in_sizes; (void)n_in; (void)out_size; (void)ws_size;
    const float* x     = (const float*)d_in[0];
    const int*   adj   = (const int*)d_in[1];     // bool -> int32
    const float* w     = (const float*)d_in[2];
    const float* a_src = (const float*)d_in[3];
    const float* a_dst = (const float*)d_in[4];
    const float* bias  = (const float*)d_in[5];
    float*       out   = (float*)d_out;

    _Float16*     h16B    = (_Float16*)d_ws;                               // 4 MB
    float*        ssrc    = (float*)((char*)d_ws + 4194304);               // 128 KB
    float*        sdst    = (float*)((char*)d_ws + 4194304 + 131072);      // 128 KB
    unsigned int* adjbits = (unsigned int*)((char*)d_ws + 4718592);        // 2 MB

    k1_proj<<<512, 256, 0, stream>>>(x, w, a_src, a_dst, adj, h16B, ssrc, sdst, adjbits);
    k2_attn<<<512, 256, 0, stream>>>(adjbits, h16B, ssrc, sdst, bias, out);
}